// Round 3
// baseline (316.703 us; speedup 1.0000x reference)
//
#include <hip/hip_runtime.h>

typedef short bf16x8 __attribute__((ext_vector_type(8)));
typedef float f32x4 __attribute__((ext_vector_type(4)));
typedef unsigned short ushort8v __attribute__((ext_vector_type(8)));
typedef unsigned short ushort4v __attribute__((ext_vector_type(4)));

__device__ __forceinline__ unsigned short f2bf(float f) {
  unsigned u = __float_as_uint(f);
  u += 0x7FFF + ((u >> 16) & 1);   // round-to-nearest-even
  return (unsigned short)(u >> 16);
}

// ---------------------------------------------------------------------------
// Kernel 0: weights -> WbT [640][512] bf16, WbT[o][c]:
//   o in [0,64)    = Wq[c][o]
//   o in [64,128)  = Wk[c][o-64]
//   o in [128,640) = Wv[c][o-128]
// ---------------------------------------------------------------------------
__global__ void wt_prep(const float* __restrict__ Wq, const float* __restrict__ Wk,
                        const float* __restrict__ Wv, unsigned short* __restrict__ WbT) {
  int idx = blockIdx.x * 256 + threadIdx.x;   // 640*512 = 327680 total
  int o = idx >> 9, c = idx & 511;
  float v;
  if (o < 64)       v = Wq[c * 64 + o];
  else if (o < 128) v = Wk[c * 64 + (o - 64)];
  else              v = Wv[(size_t)c * 512 + (o - 128)];
  WbT[idx] = f2bf(v);
}

// ---------------------------------------------------------------------------
// Kernel 1: projection GEMM  [16384,512] x [512,640] -> q,k row-major bf16 and
// v transposed vT[b][512][4096] bf16.
// 128x128 tile, 4 waves (each 64x64), K-step 64. A staged fp32->bf16 in LDS.
// B fragments read directly from global WbT (L1/L2 resident).
// ---------------------------------------------------------------------------
__global__ __launch_bounds__(256, 2) void proj_gemm(
    const float* __restrict__ x, const unsigned short* __restrict__ WbT,
    unsigned short* __restrict__ q, unsigned short* __restrict__ k,
    unsigned short* __restrict__ vT) {
  __shared__ unsigned short As[128][72];   // 64 + 8 pad
  const int tid = threadIdx.x;
  const int wid = tid >> 6, lane = tid & 63;
  const int l15 = lane & 15, l4 = lane >> 4;
  const int mtile = blockIdx.x, ntile = blockIdx.y;
  const int rbase = mtile * 128;
  const int wr = (wid >> 1) * 64, wc = (wid & 1) * 64;

  f32x4 acc[4][4] = {};

  const int arow = tid >> 2;         // 0..63
  const int akof = (tid & 3) * 16;   // 0,16,32,48

  for (int kb = 0; kb < 512; kb += 64) {
    f32x4 t0[2][4];
#pragma unroll
    for (int pass = 0; pass < 2; ++pass) {
      const float* src = x + (size_t)(rbase + pass * 64 + arow) * 512 + kb + akof;
#pragma unroll
      for (int i = 0; i < 4; ++i) t0[pass][i] = *(const f32x4*)(src + i * 4);
    }
    __syncthreads();   // prior iteration's LDS reads done
#pragma unroll
    for (int pass = 0; pass < 2; ++pass) {
      unsigned short tmp[16];
#pragma unroll
      for (int i = 0; i < 4; ++i)
#pragma unroll
        for (int j = 0; j < 4; ++j) tmp[i * 4 + j] = f2bf(t0[pass][i][j]);
      unsigned short* dst = &As[pass * 64 + arow][akof];
      *(ushort8v*)(dst)     = *(ushort8v*)(tmp);
      *(ushort8v*)(dst + 8) = *(ushort8v*)(tmp + 8);
    }
    __syncthreads();

    bf16x8 af[4][2], bfr[4][2];
#pragma unroll
    for (int mr = 0; mr < 4; ++mr)
#pragma unroll
      for (int ks = 0; ks < 2; ++ks)
        af[mr][ks] = *(const bf16x8*)&As[wr + mr * 16 + l15][ks * 32 + l4 * 8];
#pragma unroll
    for (int nc = 0; nc < 4; ++nc)
#pragma unroll
      for (int ks = 0; ks < 2; ++ks) {
        int col = ntile * 128 + wc + nc * 16 + l15;
        bfr[nc][ks] = *(const bf16x8*)(WbT + (size_t)col * 512 + kb + ks * 32 + l4 * 8);
      }
#pragma unroll
    for (int ks = 0; ks < 2; ++ks)
#pragma unroll
      for (int mr = 0; mr < 4; ++mr)
#pragma unroll
        for (int nc = 0; nc < 4; ++nc)
          acc[mr][nc] = __builtin_amdgcn_mfma_f32_16x16x32_bf16(af[mr][ks], bfr[nc][ks],
                                                                acc[mr][nc], 0, 0, 0);
  }

  if (ntile == 0) {
    // cols 0..63 -> q (waves with wc==0), cols 64..127 -> k (wc==64)
    unsigned short* dst = (wid & 1) ? k : q;
#pragma unroll
    for (int mr = 0; mr < 4; ++mr)
#pragma unroll
      for (int nc = 0; nc < 4; ++nc)
#pragma unroll
        for (int r = 0; r < 4; ++r) {
          int grow = rbase + wr + mr * 16 + l4 * 4 + r;
          int col = nc * 16 + l15;   // local col inside q or k
          dst[(size_t)grow * 64 + col] = f2bf(acc[mr][nc][r]);
        }
  } else {
    // v part, written transposed: vT[b][col][m], 4 consecutive m packed per lane
#pragma unroll
    for (int mr = 0; mr < 4; ++mr)
#pragma unroll
      for (int nc = 0; nc < 4; ++nc) {
        int col = ntile * 128 + wc + nc * 16 + l15 - 128;   // 0..511
        int grow = rbase + wr + mr * 16 + l4 * 4;
        int b = grow >> 12, m = grow & 4095;
        ushort4v pk;
#pragma unroll
        for (int r = 0; r < 4; ++r) pk[r] = f2bf(acc[mr][nc][r]);
        *(ushort4v*)(vT + ((size_t)b * 512 + col) * 4096 + m) = pk;
      }
  }
}

// ---------------------------------------------------------------------------
// Kernel 2: fused sigmoid-attention.
// Block = (128 q-rows) x (128 v-cols) for one batch; loop m in chunks of 128.
// 4 waves: S-phase each wave does 32 rows x 128 m; PV-phase each wave does a
// 64x64 output quadrant. P round-trips through LDS (padded, conflict-free).
// ---------------------------------------------------------------------------
__global__ __launch_bounds__(256, 2) void attn_fused(
    const float* __restrict__ x, const unsigned short* __restrict__ q,
    const unsigned short* __restrict__ k, const unsigned short* __restrict__ vT,
    const float* __restrict__ gamma, float* __restrict__ out) {
  __shared__ unsigned short P[128][136];   // +8 pad -> b128 reads 2-way (free)
  const int tid = threadIdx.x, wid = tid >> 6, lane = tid & 63;
  const int l15 = lane & 15, l4 = lane >> 4;
  const int rt = blockIdx.x, ct = blockIdx.y, b = blockIdx.z;
  const int rbase = rt * 128;
  const unsigned short* qb = q + (size_t)b * 4096 * 64;
  const unsigned short* kp = k + (size_t)b * 4096 * 64;
  const unsigned short* vb = vT + (size_t)b * 512 * 4096;
  const float gv = gamma[0];
  const int wr = (wid >> 1) * 64, wc = (wid & 1) * 64;

  // q fragments for this wave's 32 S-rows (fixed for whole block)
  bf16x8 qf[2][2];
#pragma unroll
  for (int rf = 0; rf < 2; ++rf)
#pragma unroll
    for (int ks = 0; ks < 2; ++ks)
      qf[rf][ks] = *(const bf16x8*)(qb + (size_t)(rbase + wid * 32 + rf * 16 + l15) * 64 +
                                    ks * 32 + l4 * 8);

  f32x4 oacc[4][4] = {};

  for (int mb = 0; mb < 4096; mb += 128) {
    // ---- S = q . k^T for rows [wid*32, +32) x m [mb, mb+128) ----
    f32x4 sacc[2][8] = {};
#pragma unroll
    for (int ks = 0; ks < 2; ++ks)
#pragma unroll
      for (int cf = 0; cf < 8; ++cf) {
        bf16x8 kf = *(const bf16x8*)(kp + (size_t)(mb + cf * 16 + l15) * 64 + ks * 32 + l4 * 8);
#pragma unroll
        for (int rf = 0; rf < 2; ++rf)
          sacc[rf][cf] = __builtin_amdgcn_mfma_f32_16x16x32_bf16(qf[rf][ks], kf,
                                                                 sacc[rf][cf], 0, 0, 0);
      }
    __syncthreads();   // previous iteration's P reads complete
    // ---- sigmoid + write P (bf16) ----
#pragma unroll
    for (int rf = 0; rf < 2; ++rf)
#pragma unroll
      for (int cf = 0; cf < 8; ++cf)
#pragma unroll
        for (int r = 0; r < 4; ++r) {
          float s = sacc[rf][cf][r];
          float p = __builtin_amdgcn_rcpf(1.0f + __builtin_amdgcn_exp2f(-1.44269504f * s));
          P[wid * 32 + rf * 16 + l4 * 4 + r][cf * 16 + l15] = f2bf(p);
        }
    __syncthreads();
    // ---- O += P . v ----
#pragma unroll
    for (int kk = 0; kk < 4; ++kk) {
      bf16x8 af[4], bfr[4];
#pragma unroll
      for (int mr = 0; mr < 4; ++mr)
        af[mr] = *(const bf16x8*)&P[wr + mr * 16 + l15][kk * 32 + l4 * 8];
#pragma unroll
      for (int nc = 0; nc < 4; ++nc)
        bfr[nc] = *(const bf16x8*)(vb + (size_t)(ct * 128 + wc + nc * 16 + l15) * 4096 +
                                   mb + kk * 32 + l4 * 8);
#pragma unroll
      for (int mr = 0; mr < 4; ++mr)
#pragma unroll
        for (int nc = 0; nc < 4; ++nc)
          oacc[mr][nc] = __builtin_amdgcn_mfma_f32_16x16x32_bf16(af[mr], bfr[nc],
                                                                 oacc[mr][nc], 0, 0, 0);
    }
  }

  // ---- epilogue: out = gamma * O + x ----
#pragma unroll
  for (int mr = 0; mr < 4; ++mr)
#pragma unroll
    for (int nc = 0; nc < 4; ++nc)
#pragma unroll
      for (int r = 0; r < 4; ++r) {
        int grow = rbase + wr + mr * 16 + l4 * 4 + r;
        int col = ct * 128 + wc + nc * 16 + l15;
        size_t idx = ((size_t)b * 4096 + grow) * 512 + col;
        out[idx] = gv * oacc[mr][nc][r] + x[idx];
      }
}

extern "C" void kernel_launch(void* const* d_in, const int* in_sizes, int n_in,
                              void* d_out, int out_size, void* d_ws, size_t ws_size,
                              hipStream_t stream) {
  const float* x     = (const float*)d_in[0];
  const float* Wq    = (const float*)d_in[1];
  const float* Wk    = (const float*)d_in[2];
  const float* Wv    = (const float*)d_in[3];
  const float* gamma = (const float*)d_in[4];
  float* out = (float*)d_out;

  char* ws = (char*)d_ws;
  unsigned short* qbuf = (unsigned short*)(ws);                       // 2 MB
  unsigned short* kbuf = (unsigned short*)(ws + (2ull << 20));        // 2 MB
  unsigned short* vT   = (unsigned short*)(ws + (4ull << 20));        // 16 MB
  unsigned short* WbT  = (unsigned short*)(ws + (20ull << 20));       // 640 KB

  hipLaunchKernelGGL(wt_prep, dim3(1280), dim3(256), 0, stream, Wq, Wk, Wv, WbT);
  hipLaunchKernelGGL(proj_gemm, dim3(128, 5), dim3(256), 0, stream, x, WbT, qbuf, kbuf, vT);
  hipLaunchKernelGGL(attn_fused, dim3(32, 4, 4), dim3(256), 0, stream,
                     x, qbuf, kbuf, vT, gamma, out);
}

// Round 4
// 194.585 us; speedup vs baseline: 1.6276x; 1.6276x over previous
//
#include <hip/hip_runtime.h>

typedef short bf16x8 __attribute__((ext_vector_type(8)));
typedef float f32x4 __attribute__((ext_vector_type(4)));
typedef unsigned short ushort8v __attribute__((ext_vector_type(8)));
typedef unsigned short ushort4v __attribute__((ext_vector_type(4)));

__device__ __forceinline__ unsigned short f2bf(float f) {
  unsigned u = __float_as_uint(f);
  u += 0x7FFF + ((u >> 16) & 1);   // round-to-nearest-even
  return (unsigned short)(u >> 16);
}

// ---------------------------------------------------------------------------
// Kernel 0: weights -> WbT [640][512] bf16, WbT[o][c]:
//   o in [0,64)    = Wq[c][o] * log2(e)   (folds sigmoid exp2 scale into q)
//   o in [64,128)  = Wk[c][o-64]
//   o in [128,640) = Wv[c][o-128]
// ---------------------------------------------------------------------------
__global__ void wt_prep(const float* __restrict__ Wq, const float* __restrict__ Wk,
                        const float* __restrict__ Wv, unsigned short* __restrict__ WbT) {
  int idx = blockIdx.x * 256 + threadIdx.x;   // 640*512 = 327680 total
  int o = idx >> 9, c = idx & 511;
  float v;
  if (o < 64)       v = Wq[c * 64 + o] * 1.44269504f;
  else if (o < 128) v = Wk[c * 64 + (o - 64)];
  else              v = Wv[(size_t)c * 512 + (o - 128)];
  WbT[idx] = f2bf(v);
}

// ---------------------------------------------------------------------------
// Kernel 1: projection GEMM  [16384,512] x [512,640] -> q,k row-major bf16 and
// v transposed vT[b][512][4096] bf16. (unchanged from round 0 — validated)
// ---------------------------------------------------------------------------
__global__ __launch_bounds__(256, 2) void proj_gemm(
    const float* __restrict__ x, const unsigned short* __restrict__ WbT,
    unsigned short* __restrict__ q, unsigned short* __restrict__ k,
    unsigned short* __restrict__ vT) {
  __shared__ unsigned short As[128][72];   // 64 + 8 pad
  const int tid = threadIdx.x;
  const int wid = tid >> 6, lane = tid & 63;
  const int l15 = lane & 15, l4 = lane >> 4;
  const int mtile = blockIdx.x, ntile = blockIdx.y;
  const int rbase = mtile * 128;
  const int wr = (wid >> 1) * 64, wc = (wid & 1) * 64;

  f32x4 acc[4][4] = {};

  const int arow = tid >> 2;         // 0..63
  const int akof = (tid & 3) * 16;   // 0,16,32,48

  for (int kb = 0; kb < 512; kb += 64) {
    f32x4 t0[2][4];
#pragma unroll
    for (int pass = 0; pass < 2; ++pass) {
      const float* src = x + (size_t)(rbase + pass * 64 + arow) * 512 + kb + akof;
#pragma unroll
      for (int i = 0; i < 4; ++i) t0[pass][i] = *(const f32x4*)(src + i * 4);
    }
    __syncthreads();   // prior iteration's LDS reads done
#pragma unroll
    for (int pass = 0; pass < 2; ++pass) {
      unsigned short tmp[16];
#pragma unroll
      for (int i = 0; i < 4; ++i)
#pragma unroll
        for (int j = 0; j < 4; ++j) tmp[i * 4 + j] = f2bf(t0[pass][i][j]);
      unsigned short* dst = &As[pass * 64 + arow][akof];
      *(ushort8v*)(dst)     = *(ushort8v*)(tmp);
      *(ushort8v*)(dst + 8) = *(ushort8v*)(tmp + 8);
    }
    __syncthreads();

    bf16x8 af[4][2], bfr[4][2];
#pragma unroll
    for (int mr = 0; mr < 4; ++mr)
#pragma unroll
      for (int ks = 0; ks < 2; ++ks)
        af[mr][ks] = *(const bf16x8*)&As[wr + mr * 16 + l15][ks * 32 + l4 * 8];
#pragma unroll
    for (int nc = 0; nc < 4; ++nc)
#pragma unroll
      for (int ks = 0; ks < 2; ++ks) {
        int col = ntile * 128 + wc + nc * 16 + l15;
        bfr[nc][ks] = *(const bf16x8*)(WbT + (size_t)col * 512 + kb + ks * 32 + l4 * 8);
      }
#pragma unroll
    for (int ks = 0; ks < 2; ++ks)
#pragma unroll
      for (int mr = 0; mr < 4; ++mr)
#pragma unroll
        for (int nc = 0; nc < 4; ++nc)
          acc[mr][nc] = __builtin_amdgcn_mfma_f32_16x16x32_bf16(af[mr][ks], bfr[nc][ks],
                                                                acc[mr][nc], 0, 0, 0);
  }

  if (ntile == 0) {
    unsigned short* dst = (wid & 1) ? k : q;
#pragma unroll
    for (int mr = 0; mr < 4; ++mr)
#pragma unroll
      for (int nc = 0; nc < 4; ++nc)
#pragma unroll
        for (int r = 0; r < 4; ++r) {
          int grow = rbase + wr + mr * 16 + l4 * 4 + r;
          int col = nc * 16 + l15;
          dst[(size_t)grow * 64 + col] = f2bf(acc[mr][nc][r]);
        }
  } else {
#pragma unroll
    for (int mr = 0; mr < 4; ++mr)
#pragma unroll
      for (int nc = 0; nc < 4; ++nc) {
        int col = ntile * 128 + wc + nc * 16 + l15 - 128;   // 0..511
        int grow = rbase + wr + mr * 16 + l4 * 4;
        int b = grow >> 12, m = grow & 4095;
        ushort4v pk;
#pragma unroll
        for (int r = 0; r < 4; ++r) pk[r] = f2bf(acc[mr][nc][r]);
        *(ushort4v*)(vT + ((size_t)b * 512 + col) * 4096 + m) = pk;
      }
  }
}

// ---------------------------------------------------------------------------
// Kernel 2 (v2): fused sigmoid-attention, LDS-staged + double-buffered.
// Grid (32 rt, 4 ct, 4 b) = 512 blocks x 512 threads (8 waves) = 16 waves/CU.
// Block output: 128 q-rows x 128 v-cols; m-loop in chunks of MB=64.
// K,V chunks reg-staged into dbuf LDS (loads issued at chunk top, written
// after PV -> HBM latency hides under compute). P via padded LDS.
// S-phase: each wave 16 rows x 64 m (8 MFMA). PV: wave tile 32x64 (16 MFMA).
// ---------------------------------------------------------------------------
__global__ __launch_bounds__(512, 4) void attn_fused(
    const float* __restrict__ x, const unsigned short* __restrict__ q,
    const unsigned short* __restrict__ k, const unsigned short* __restrict__ vT,
    const float* __restrict__ gamma, float* __restrict__ out) {
  __shared__ unsigned short Ks[2][64][72];    // [m][d]   18.4 KB
  __shared__ unsigned short Vs[2][128][72];   // [col][m] 36.9 KB
  __shared__ unsigned short Ps[128][72];      // [row][m] 18.4 KB
  const int tid = threadIdx.x, wid = tid >> 6, lane = tid & 63;
  const int l15 = lane & 15, l4 = lane >> 4;
  const int rt = blockIdx.x, ct = blockIdx.y, b = blockIdx.z;
  const int rbase = rt * 128, cbase = ct * 128;
  const unsigned short* qb = q + (size_t)b * 4096 * 64;
  const unsigned short* kp = k + (size_t)b * 4096 * 64;
  const unsigned short* vb = vT + (size_t)b * 512 * 4096;
  const float gv = gamma[0];
  const int wr = (wid >> 1) * 32, wc = (wid & 1) * 64;   // PV wave tile 32x64

  // staging indices (whole block cooperates)
  const int krow = tid >> 3, kseg = (tid & 7) * 8;        // K: 64 rows x 128B
  const int vcol = tid >> 2, vseg = (tid & 3) * 16;       // V: 128 cols x 128B

  // q fragments: this wave's 16 S-rows, fixed for the whole block
  bf16x8 qf[2];
#pragma unroll
  for (int ks = 0; ks < 2; ++ks)
    qf[ks] = *(const bf16x8*)(qb + (size_t)(rbase + wid * 16 + l15) * 64 + ks * 32 + l4 * 8);

  // ---- prologue: stage chunk 0 into buf 0 ----
  {
    bf16x8 kr = *(const bf16x8*)(kp + (size_t)krow * 64 + kseg);
    bf16x8 v0 = *(const bf16x8*)(vb + (size_t)(cbase + vcol) * 4096 + vseg);
    bf16x8 v1 = *(const bf16x8*)(vb + (size_t)(cbase + vcol) * 4096 + vseg + 8);
    *(bf16x8*)&Ks[0][krow][kseg] = kr;
    *(bf16x8*)&Vs[0][vcol][vseg] = v0;
    *(bf16x8*)&Vs[0][vcol][vseg + 8] = v1;
  }
  __syncthreads();

  f32x4 oacc[2][4] = {};
  int cur = 0;

  for (int it = 0; it < 64; ++it) {
    const int mb_next = (it + 1) * 64;
    const bool pf = (it < 63);
    // ---- issue next chunk's global loads EARLY (consumed after PV) ----
    bf16x8 kr, v0, v1;
    if (pf) {
      kr = *(const bf16x8*)(kp + (size_t)(mb_next + krow) * 64 + kseg);
      v0 = *(const bf16x8*)(vb + (size_t)(cbase + vcol) * 4096 + mb_next + vseg);
      v1 = *(const bf16x8*)(vb + (size_t)(cbase + vcol) * 4096 + mb_next + vseg + 8);
    }

    // ---- S = q.k^T : wave rows [wid*16,+16) x m [0,64) of this chunk ----
    f32x4 sacc[4] = {};
#pragma unroll
    for (int ks = 0; ks < 2; ++ks)
#pragma unroll
      for (int cf = 0; cf < 4; ++cf) {
        bf16x8 kf = *(const bf16x8*)&Ks[cur][cf * 16 + l15][ks * 32 + l4 * 8];
        sacc[cf] = __builtin_amdgcn_mfma_f32_16x16x32_bf16(qf[ks], kf, sacc[cf], 0, 0, 0);
      }
    // ---- sigmoid (q pre-scaled by log2e) + P write ----
#pragma unroll
    for (int cf = 0; cf < 4; ++cf)
#pragma unroll
      for (int r = 0; r < 4; ++r) {
        float s = sacc[cf][r];
        float p = __builtin_amdgcn_rcpf(1.0f + __builtin_amdgcn_exp2f(-s));
        Ps[wid * 16 + l4 * 4 + r][cf * 16 + l15] = f2bf(p);
      }
    __syncthreads();   // P visible; all waves done reading Ks[cur]

    // ---- O += P . v  (wave tile 32 rows x 64 cols) ----
#pragma unroll
    for (int ks = 0; ks < 2; ++ks) {
      bf16x8 af[2], bfr[4];
#pragma unroll
      for (int mr = 0; mr < 2; ++mr)
        af[mr] = *(const bf16x8*)&Ps[wr + mr * 16 + l15][ks * 32 + l4 * 8];
#pragma unroll
      for (int nc = 0; nc < 4; ++nc)
        bfr[nc] = *(const bf16x8*)&Vs[cur][wc + nc * 16 + l15][ks * 32 + l4 * 8];
#pragma unroll
      for (int mr = 0; mr < 2; ++mr)
#pragma unroll
        for (int nc = 0; nc < 4; ++nc)
          oacc[mr][nc] = __builtin_amdgcn_mfma_f32_16x16x32_bf16(af[mr], bfr[nc],
                                                                 oacc[mr][nc], 0, 0, 0);
    }

    // ---- write prefetched chunk into the other buffer ----
    if (pf) {
      *(bf16x8*)&Ks[cur ^ 1][krow][kseg] = kr;
      *(bf16x8*)&Vs[cur ^ 1][vcol][vseg] = v0;
      *(bf16x8*)&Vs[cur ^ 1][vcol][vseg + 8] = v1;
    }
    __syncthreads();   // next buf ready; P reads done before next P write
    cur ^= 1;
  }

  // ---- epilogue: out = gamma * O + x ----
#pragma unroll
  for (int mr = 0; mr < 2; ++mr)
#pragma unroll
    for (int nc = 0; nc < 4; ++nc)
#pragma unroll
      for (int r = 0; r < 4; ++r) {
        int grow = rbase + wr + mr * 16 + l4 * 4 + r;
        int col = cbase + wc + nc * 16 + l15;
        size_t idx = ((size_t)b * 4096 + grow) * 512 + col;
        out[idx] = gv * oacc[mr][nc][r] + x[idx];
      }
}

extern "C" void kernel_launch(void* const* d_in, const int* in_sizes, int n_in,
                              void* d_out, int out_size, void* d_ws, size_t ws_size,
                              hipStream_t stream) {
  const float* x     = (const float*)d_in[0];
  const float* Wq    = (const float*)d_in[1];
  const float* Wk    = (const float*)d_in[2];
  const float* Wv    = (const float*)d_in[3];
  const float* gamma = (const float*)d_in[4];
  float* out = (float*)d_out;

  char* ws = (char*)d_ws;
  unsigned short* qbuf = (unsigned short*)(ws);                       // 2 MB
  unsigned short* kbuf = (unsigned short*)(ws + (2ull << 20));        // 2 MB
  unsigned short* vT   = (unsigned short*)(ws + (4ull << 20));        // 16 MB
  unsigned short* WbT  = (unsigned short*)(ws + (20ull << 20));       // 640 KB

  hipLaunchKernelGGL(wt_prep, dim3(1280), dim3(256), 0, stream, Wq, Wk, Wv, WbT);
  hipLaunchKernelGGL(proj_gemm, dim3(128, 5), dim3(256), 0, stream, x, WbT, qbuf, kbuf, vT);
  hipLaunchKernelGGL(attn_fused, dim3(32, 4, 4), dim3(512), 0, stream,
                     x, qbuf, kbuf, vT, gamma, out);
}

// Round 5
// 161.965 us; speedup vs baseline: 1.9554x; 1.2014x over previous
//
#include <hip/hip_runtime.h>

typedef short bf16x8 __attribute__((ext_vector_type(8)));
typedef float f32x4 __attribute__((ext_vector_type(4)));
typedef unsigned short ushort8v __attribute__((ext_vector_type(8)));
typedef unsigned short ushort4v __attribute__((ext_vector_type(4)));

__device__ __forceinline__ unsigned short f2bf(float f) {
  unsigned u = __float_as_uint(f);
  u += 0x7FFF + ((u >> 16) & 1);   // round-to-nearest-even
  return (unsigned short)(u >> 16);
}

// ---------------------------------------------------------------------------
// Kernel 0: weights -> WbT [640][512] bf16, WbT[o][c]:
//   o in [0,64)    = Wq[c][o] * log2(e)   (folds sigmoid exp2 scale into q)
//   o in [64,128)  = Wk[c][o-64]
//   o in [128,640) = Wv[c][o-128]
// ---------------------------------------------------------------------------
__global__ void wt_prep(const float* __restrict__ Wq, const float* __restrict__ Wk,
                        const float* __restrict__ Wv, unsigned short* __restrict__ WbT) {
  int idx = blockIdx.x * 256 + threadIdx.x;   // 640*512 = 327680 total
  int o = idx >> 9, c = idx & 511;
  float v;
  if (o < 64)       v = Wq[c * 64 + o] * 1.44269504f;
  else if (o < 128) v = Wk[c * 64 + (o - 64)];
  else              v = Wv[(size_t)c * 512 + (o - 128)];
  WbT[idx] = f2bf(v);
}

// ---------------------------------------------------------------------------
// Kernel 1: projection GEMM  [16384,512] x [512,640] -> q,k row-major bf16 and
// v transposed vT[b][512][4096] bf16. (validated rounds 3-4, unchanged)
// ---------------------------------------------------------------------------
__global__ __launch_bounds__(256, 2) void proj_gemm(
    const float* __restrict__ x, const unsigned short* __restrict__ WbT,
    unsigned short* __restrict__ q, unsigned short* __restrict__ k,
    unsigned short* __restrict__ vT) {
  __shared__ unsigned short As[128][72];   // 64 + 8 pad
  const int tid = threadIdx.x;
  const int wid = tid >> 6, lane = tid & 63;
  const int l15 = lane & 15, l4 = lane >> 4;
  const int mtile = blockIdx.x, ntile = blockIdx.y;
  const int rbase = mtile * 128;
  const int wr = (wid >> 1) * 64, wc = (wid & 1) * 64;

  f32x4 acc[4][4] = {};

  const int arow = tid >> 2;         // 0..63
  const int akof = (tid & 3) * 16;   // 0,16,32,48

  for (int kb = 0; kb < 512; kb += 64) {
    f32x4 t0[2][4];
#pragma unroll
    for (int pass = 0; pass < 2; ++pass) {
      const float* src = x + (size_t)(rbase + pass * 64 + arow) * 512 + kb + akof;
#pragma unroll
      for (int i = 0; i < 4; ++i) t0[pass][i] = *(const f32x4*)(src + i * 4);
    }
    __syncthreads();   // prior iteration's LDS reads done
#pragma unroll
    for (int pass = 0; pass < 2; ++pass) {
      unsigned short tmp[16];
#pragma unroll
      for (int i = 0; i < 4; ++i)
#pragma unroll
        for (int j = 0; j < 4; ++j) tmp[i * 4 + j] = f2bf(t0[pass][i][j]);
      unsigned short* dst = &As[pass * 64 + arow][akof];
      *(ushort8v*)(dst)     = *(ushort8v*)(tmp);
      *(ushort8v*)(dst + 8) = *(ushort8v*)(tmp + 8);
    }
    __syncthreads();

    bf16x8 af[4][2], bfr[4][2];
#pragma unroll
    for (int mr = 0; mr < 4; ++mr)
#pragma unroll
      for (int ks = 0; ks < 2; ++ks)
        af[mr][ks] = *(const bf16x8*)&As[wr + mr * 16 + l15][ks * 32 + l4 * 8];
#pragma unroll
    for (int nc = 0; nc < 4; ++nc)
#pragma unroll
      for (int ks = 0; ks < 2; ++ks) {
        int col = ntile * 128 + wc + nc * 16 + l15;
        bfr[nc][ks] = *(const bf16x8*)(WbT + (size_t)col * 512 + kb + ks * 32 + l4 * 8);
      }
#pragma unroll
    for (int ks = 0; ks < 2; ++ks)
#pragma unroll
      for (int mr = 0; mr < 4; ++mr)
#pragma unroll
        for (int nc = 0; nc < 4; ++nc)
          acc[mr][nc] = __builtin_amdgcn_mfma_f32_16x16x32_bf16(af[mr][ks], bfr[nc][ks],
                                                                acc[mr][nc], 0, 0, 0);
  }

  if (ntile == 0) {
    unsigned short* dst = (wid & 1) ? k : q;
#pragma unroll
    for (int mr = 0; mr < 4; ++mr)
#pragma unroll
      for (int nc = 0; nc < 4; ++nc)
#pragma unroll
        for (int r = 0; r < 4; ++r) {
          int grow = rbase + wr + mr * 16 + l4 * 4 + r;
          int col = nc * 16 + l15;
          dst[(size_t)grow * 64 + col] = f2bf(acc[mr][nc][r]);
        }
  } else {
#pragma unroll
    for (int mr = 0; mr < 4; ++mr)
#pragma unroll
      for (int nc = 0; nc < 4; ++nc) {
        int col = ntile * 128 + wc + nc * 16 + l15 - 128;   // 0..511
        int grow = rbase + wr + mr * 16 + l4 * 4;
        int b = grow >> 12, m = grow & 4095;
        ushort4v pk;
#pragma unroll
        for (int r = 0; r < 4; ++r) pk[r] = f2bf(acc[mr][nc][r]);
        *(ushort4v*)(vT + ((size_t)b * 512 + col) * 4096 + m) = pk;
      }
  }
}

// ---------------------------------------------------------------------------
// Kernel 2 (v3): fused sigmoid-attention.
// Grid (32 rt, 2 ct, 4 b) = 256 blocks x 512 threads (8 waves), 1 block/CU.
// Block output: 128 q-rows x 256 v-cols; m-loop chunks of MB=64.
// S-phase SWAPPED: mfma(K, Q) -> lane holds 4 consecutive m per q-row ->
// sigmoid + pack -> ds_write_b64 (conflict-floor). Q in registers (8 frags).
// PV: wave tile 64x64 (4x4 frags). 2 barriers/chunk; K ds_write between
// barrier A and PV, V ds_write after barrier B; global loads issued at top.
// LDS 63 KB static, all strides 144 B (=36 banks, 16B-aligned, 2-way reads).
// ---------------------------------------------------------------------------
__global__ __launch_bounds__(512, 2) void attn_fused(
    const float* __restrict__ x, const unsigned short* __restrict__ q,
    const unsigned short* __restrict__ k, const unsigned short* __restrict__ vT,
    const float* __restrict__ gamma, float* __restrict__ out) {
  __shared__ unsigned short Ks[64][72];    //  9.2 KB  [m][d]
  __shared__ unsigned short Vs[256][72];   // 36.9 KB  [col][m]
  __shared__ unsigned short Ps[128][72];   // 18.4 KB  [row][m]
  const int tid = threadIdx.x, w = tid >> 6, lane = tid & 63;
  const int l15 = lane & 15, l4 = lane >> 4;
  const int rhalf = w >> 2;      // 0..1: q-row half (S) and PV row-group
  const int mt = w & 3;          // 0..3: m-tile (S) and PV col-group
  const int rt = blockIdx.x, ct = blockIdx.y, b = blockIdx.z;
  const int rbase = rt * 128, cbase = ct * 256;
  const unsigned short* qb = q + (size_t)b * 4096 * 64;
  const unsigned short* kp = k + (size_t)b * 4096 * 64;
  const unsigned short* vb = vT + (size_t)b * 512 * 4096;
  const float gv = gamma[0];

  // staging assignments
  const int kst_m = tid >> 3, kst_d = (tid & 7) * 8;    // K: 16B/thread
  const int vst_c = tid >> 1, vst_h = (tid & 1) * 32;   // V: 64B/thread

  // q fragments (register-resident all 64 chunks): rows rhalf*64 + rf*16 + l15
  bf16x8 qf[4][2];
#pragma unroll
  for (int rf = 0; rf < 4; ++rf)
#pragma unroll
    for (int ks = 0; ks < 2; ++ks)
      qf[rf][ks] = *(const bf16x8*)(qb +
          (size_t)(rbase + rhalf * 64 + rf * 16 + l15) * 64 + ks * 32 + l4 * 8);

  // ---- prologue: stage chunk 0 ----
  {
    bf16x8 kreg = *(const bf16x8*)(kp + (size_t)kst_m * 64 + kst_d);
    bf16x8 vreg[4];
#pragma unroll
    for (int i = 0; i < 4; ++i)
      vreg[i] = *(const bf16x8*)(vb + (size_t)(cbase + vst_c) * 4096 + vst_h + i * 8);
    *(bf16x8*)&Ks[kst_m][kst_d] = kreg;
#pragma unroll
    for (int i = 0; i < 4; ++i) *(bf16x8*)&Vs[vst_c][vst_h + i * 8] = vreg[i];
  }
  __syncthreads();

  f32x4 oacc[4][4] = {};

  for (int it = 0; it < 64; ++it) {
    const int mb_n = (it + 1) * 64;
    const bool pf = (it < 63);
    bf16x8 kreg; bf16x8 vreg[4];
    if (pf) {   // issue next chunk's global loads early (T14)
      kreg = *(const bf16x8*)(kp + (size_t)(mb_n + kst_m) * 64 + kst_d);
#pragma unroll
      for (int i = 0; i < 4; ++i)
        vreg[i] = *(const bf16x8*)(vb + (size_t)(cbase + vst_c) * 4096 + mb_n + vst_h + i * 8);
    }

    // ---- S^T = K . Q^T : wave computes m-tile mt (16 m) x 64 q-rows ----
    f32x4 sacc[4] = {};
#pragma unroll
    for (int ks = 0; ks < 2; ++ks) {
      bf16x8 kf = *(const bf16x8*)&Ks[mt * 16 + l15][ks * 32 + l4 * 8];
#pragma unroll
      for (int rf = 0; rf < 4; ++rf)
        sacc[rf] = __builtin_amdgcn_mfma_f32_16x16x32_bf16(kf, qf[rf][ks], sacc[rf], 0, 0, 0);
    }
    // sigmoid (q pre-scaled by log2e) + pack 4 consecutive m -> b64 write
#pragma unroll
    for (int rf = 0; rf < 4; ++rf) {
      ushort4v pk;
#pragma unroll
      for (int r = 0; r < 4; ++r) {
        float s = sacc[rf][r];
        pk[r] = f2bf(__builtin_amdgcn_rcpf(1.0f + __builtin_amdgcn_exp2f(-s)));
      }
      *(ushort4v*)&Ps[rhalf * 64 + rf * 16 + l15][mt * 16 + l4 * 4] = pk;
    }
    __syncthreads();   // A: Ps visible; Ks reads done

    if (pf) *(bf16x8*)&Ks[kst_m][kst_d] = kreg;   // next chunk's K (read after B)

    // ---- O += P . v : wave tile rows rhalf*64, cols mt*64 (4x4 frags) ----
#pragma unroll
    for (int kk = 0; kk < 2; ++kk) {
      bf16x8 af[4], bfr[4];
#pragma unroll
      for (int mr = 0; mr < 4; ++mr)
        af[mr] = *(const bf16x8*)&Ps[rhalf * 64 + mr * 16 + l15][kk * 32 + l4 * 8];
#pragma unroll
      for (int nc = 0; nc < 4; ++nc)
        bfr[nc] = *(const bf16x8*)&Vs[mt * 64 + nc * 16 + l15][kk * 32 + l4 * 8];
#pragma unroll
      for (int mr = 0; mr < 4; ++mr)
#pragma unroll
        for (int nc = 0; nc < 4; ++nc)
          oacc[mr][nc] = __builtin_amdgcn_mfma_f32_16x16x32_bf16(af[mr], bfr[nc],
                                                                 oacc[mr][nc], 0, 0, 0);
    }
    __syncthreads();   // B: Vs/Ps reads done

    if (pf) {   // next chunk's V (read after next A)
#pragma unroll
      for (int i = 0; i < 4; ++i) *(bf16x8*)&Vs[vst_c][vst_h + i * 8] = vreg[i];
    }
  }

  // ---- epilogue: out = gamma * O + x ----
#pragma unroll
  for (int mr = 0; mr < 4; ++mr)
#pragma unroll
    for (int nc = 0; nc < 4; ++nc)
#pragma unroll
      for (int r = 0; r < 4; ++r) {
        int grow = rbase + rhalf * 64 + mr * 16 + l4 * 4 + r;
        int col = cbase + mt * 64 + nc * 16 + l15;
        size_t idx = ((size_t)b * 4096 + grow) * 512 + col;
        out[idx] = gv * oacc[mr][nc][r] + x[idx];
      }
}

extern "C" void kernel_launch(void* const* d_in, const int* in_sizes, int n_in,
                              void* d_out, int out_size, void* d_ws, size_t ws_size,
                              hipStream_t stream) {
  const float* x     = (const float*)d_in[0];
  const float* Wq    = (const float*)d_in[1];
  const float* Wk    = (const float*)d_in[2];
  const float* Wv    = (const float*)d_in[3];
  const float* gamma = (const float*)d_in[4];
  float* out = (float*)d_out;

  char* ws = (char*)d_ws;
  unsigned short* qbuf = (unsigned short*)(ws);                       // 2 MB
  unsigned short* kbuf = (unsigned short*)(ws + (2ull << 20));        // 2 MB
  unsigned short* vT   = (unsigned short*)(ws + (4ull << 20));        // 16 MB
  unsigned short* WbT  = (unsigned short*)(ws + (20ull << 20));       // 640 KB

  hipLaunchKernelGGL(wt_prep, dim3(1280), dim3(256), 0, stream, Wq, Wk, Wv, WbT);
  hipLaunchKernelGGL(proj_gemm, dim3(128, 5), dim3(256), 0, stream, x, WbT, qbuf, kbuf, vT);
  hipLaunchKernelGGL(attn_fused, dim3(32, 2, 4), dim3(512), 0, stream,
                     x, qbuf, kbuf, vT, gamma, out);
}